// Round 1
// 398.511 us; speedup vs baseline: 1.0847x; 1.0847x over previous
//
#include <hip/hip_runtime.h>
#include <hip/hip_bf16.h>

#define S_LEN 4096
#define DH 64
#define NBATCH 4

typedef __attribute__((ext_vector_type(8))) short bf16x8;   // 8 x bf16 (4 VGPRs)
typedef __attribute__((ext_vector_type(4))) short bf16x4;   // 4 x bf16
typedef __attribute__((ext_vector_type(4))) float f32x4;

static __device__ __forceinline__ short f2bf(float x) {
  __hip_bfloat16 h = __float2bfloat16(x);
  return *reinterpret_cast<short*>(&h);
}

#define MFMA(a, b, c) __builtin_amdgcn_mfma_f32_16x16x32_bf16((a), (b), (c), 0, 0, 0)

// ---- q fp32 -> bf16 ----
__global__ __launch_bounds__(256) void cvt_q_kernel(const float* __restrict__ q,
                                                    short* __restrict__ qb) {
  int i = (blockIdx.x * 256 + threadIdx.x) * 4;
  f32x4 x = *(const f32x4*)(q + i);
  bf16x4 o;
#pragma unroll
  for (int j = 0; j < 4; ++j) o[j] = f2bf(x[j]);
  *(bf16x4*)(qb + i) = o;
}

// ---- k,v fp32 -> pre-fragmented bf16 MFMA operand layout (unchanged) ----
// For c=0..3, lane l holds the exact bf16x8 fa's MFMA needs, stored contiguously:
//   dst = ((b*128+i)*4 + c)*512 + l*8   (shorts)
// K frag c doubles as the A-operand of the swapped (S^T) MFMA: A-frag of K and
// B-frag of K^T hold identical per-lane data for 16x16x32.
__global__ __launch_bounds__(256) void cvt_frag_kernel(const float* __restrict__ k,
                                                       const float* __restrict__ v,
                                                       short* __restrict__ kfrag,
                                                       short* __restrict__ vfrag) {
  __shared__ short kt[32][80];
  __shared__ short vt[32][80];
  const int t = threadIdx.x;
  const int b = blockIdx.x >> 7;
  const int i = blockIdx.x & 127;
  const size_t src0 = ((size_t)b * S_LEN + i * 32) * DH;
  {
    const int row = t >> 3, c0 = (t & 7) * 8;
    const f32x4 xk0 = *(const f32x4*)(k + src0 + row * DH + c0);
    const f32x4 xk1 = *(const f32x4*)(k + src0 + row * DH + c0 + 4);
    const f32x4 xv0 = *(const f32x4*)(v + src0 + row * DH + c0);
    const f32x4 xv1 = *(const f32x4*)(v + src0 + row * DH + c0 + 4);
#pragma unroll
    for (int j = 0; j < 4; ++j) {
      kt[row][c0 + j] = f2bf(xk0[j]);  kt[row][c0 + 4 + j] = f2bf(xk1[j]);
      vt[row][c0 + j] = f2bf(xv0[j]);  vt[row][c0 + 4 + j] = f2bf(xv1[j]);
    }
  }
  __syncthreads();
  const int c = t >> 6, l = t & 63;
  const size_t dst = (((size_t)(b * 128 + i) * 4 + c) * 64 + l) * 8;
  {
    const int kr = ((c >> 1) * 16) + (l & 15);
    const int d0 = ((c & 1) * 32) + (l >> 4) * 8;
    *(bf16x8*)(kfrag + dst) = *(const bf16x8*)&kt[kr][d0];
  }
  {
    bf16x8 f;
    const int col = c * 16 + (l & 15);
    const int r0 = (l >> 4) * 8;
#pragma unroll
    for (int j = 0; j < 8; ++j) f[j] = vt[r0 + j][col];
    *(bf16x8*)(vfrag + dst) = f;
  }
}

// ---- main flash-attention kernel ----
// grid = B * (S/16) = 1024 blocks, 256 threads (4 waves). Block owns one 16-row
// q-tile over ALL 4096 keys; wave w, step s (32 steps) handles keys s*128+w*32.
// QK^T is computed SWAPPED (A=K-frag, B=Q-frag) so the score C-layout is
// S^T[key=quad*4+r][q=n16]: each lane's 4 mask values are CONTIGUOUS floats ->
// mask loads are 2 x dwordx4/step (was 8 scalars; mask is the 256MB HBM stream).
// K-frags + mask double-buffered 2 steps ahead; V loaded in-step (consumed
// ~400cy after issue). No barriers in the loop; per-wave LDS P round-trip only.
// Epilogue: in-block merge + normalize + plain vectorized store (no atomics,
// no memsets, no norm kernel).
__global__ __launch_bounds__(256, 4) void fa_kernel(
    const short* __restrict__ qb, const short* __restrict__ kfrag,
    const short* __restrict__ vfrag, const float* __restrict__ mask,
    float* __restrict__ out) {
  __shared__ __align__(16) short lds_p[4][16][40];
  __shared__ float lds_O[4][16][64];
  __shared__ float lds_l[4][16];

  const int tid = threadIdx.x;
  const int w = tid >> 6;
  const int lane = tid & 63;
  const int quad = lane >> 4;
  const int n16 = lane & 15;

  // XCD-contiguous remap: 1024 blocks = 8 XCDs x 128 -> each XCD sees one
  // batch-half, so its L2 keeps that batch's 1MB of K/V frags resident while
  // the mask streams through.
  const int vb = ((blockIdx.x & 7) << 7) | (blockIdx.x >> 3);
  const int b = vb >> 8;
  const int q0 = (vb & 255) << 4;

  const short* qrow = qb + (size_t)(b * S_LEN + q0 + n16) * DH;
  const bf16x8 aQ0 = *(const bf16x8*)(qrow + quad * 8);
  const bf16x8 aQ1 = *(const bf16x8*)(qrow + 32 + quad * 8);

  f32x4 O0 = {0.f, 0.f, 0.f, 0.f}, O1 = O0, O2 = O0, O3 = O0;
  float lacc = 0.f;

  const float* mrow = mask + ((size_t)b * S_LEN + q0 + n16) * S_LEN;
  const short* kfb = kfrag + (size_t)(b * 128 + w) * 2048;
  const short* vfb = vfrag + (size_t)(b * 128 + w) * 2048;

  bf16x8 kA0, kA1, kA2, kA3, kB0, kB1, kB2, kB3;
  f32x4 mA0, mA1, mB0, mB1;

#define LOAD_BK(B0, B1, B2, B3, SS)                       \
  {                                                       \
    const short* kf_ = kfb + (size_t)(SS) * 8192;         \
    B0 = *(const bf16x8*)(kf_ + lane * 8);                \
    B1 = *(const bf16x8*)(kf_ + 512 + lane * 8);          \
    B2 = *(const bf16x8*)(kf_ + 1024 + lane * 8);         \
    B3 = *(const bf16x8*)(kf_ + 1536 + lane * 8);         \
  }

#define LOAD_MASK(D0, D1, LK)                             \
  {                                                       \
    const int lk_ = (LK);                                 \
    D0 = *(const f32x4*)(mrow + lk_ + quad * 4);          \
    D1 = *(const f32x4*)(mrow + lk_ + 16 + quad * 4);     \
  }

#define FA_STEP(B0, B1, B2, B3, M0, M1, SS)                                \
  {                                                                        \
    const short* vf_ = vfb + (size_t)(SS) * 8192;                          \
    const bf16x8 v0 = *(const bf16x8*)(vf_ + lane * 8);                    \
    const bf16x8 v1 = *(const bf16x8*)(vf_ + 512 + lane * 8);              \
    const bf16x8 v2 = *(const bf16x8*)(vf_ + 1024 + lane * 8);             \
    const bf16x8 v3 = *(const bf16x8*)(vf_ + 1536 + lane * 8);             \
    const f32x4 z = {0.f, 0.f, 0.f, 0.f};                                  \
    f32x4 s0 = MFMA(B0, aQ0, z); s0 = MFMA(B1, aQ1, s0);                   \
    f32x4 s1 = MFMA(B2, aQ0, z); s1 = MFMA(B3, aQ1, s1);                   \
    LOAD_BK(B0, B1, B2, B3, ((SS) + 2) & 31); /* prefetch, regs now dead */\
    float p0_[4], p1_[4];                                                  \
    _Pragma("unroll") for (int r = 0; r < 4; ++r) {                        \
      p0_[r] = __expf(s0[r] * 0.125f * M0[r]);                             \
      p1_[r] = __expf(s1[r] * 0.125f * M1[r]);                             \
      lacc += p0_[r] + p1_[r];                                             \
    }                                                                      \
    LOAD_MASK(M0, M1, (((SS) + 2) * 128 + w * 32) & 4095); /* prefetch */  \
    bf16x4 w0_, w1_;                                                       \
    _Pragma("unroll") for (int r = 0; r < 4; ++r) {                        \
      w0_[r] = f2bf(p0_[r]); w1_[r] = f2bf(p1_[r]);                        \
    }                                                                      \
    *(bf16x4*)&lds_p[w][n16][quad * 4] = w0_;                              \
    *(bf16x4*)&lds_p[w][n16][16 + quad * 4] = w1_;                         \
    const bf16x8 aP = *(const bf16x8*)&lds_p[w][n16][quad * 8];            \
    O0 = MFMA(aP, v0, O0); O1 = MFMA(aP, v1, O1);                          \
    O2 = MFMA(aP, v2, O2); O3 = MFMA(aP, v3, O3);                          \
  }

  LOAD_BK(kA0, kA1, kA2, kA3, 0);
  LOAD_BK(kB0, kB1, kB2, kB3, 1);
  LOAD_MASK(mA0, mA1, w * 32);
  LOAD_MASK(mB0, mB1, 128 + w * 32);

#pragma unroll 1
  for (int it = 0; it < 16; ++it) {
    const int s2 = it * 2;
    FA_STEP(kA0, kA1, kA2, kA3, mA0, mA1, s2);
    FA_STEP(kB0, kB1, kB2, kB3, mB0, mB1, s2 + 1);
  }
#undef LOAD_BK
#undef LOAD_MASK
#undef FA_STEP

  // wave-local row-sum: lane holds q=n16; fold the 4 quads (keys) together
  lacc += __shfl_xor(lacc, 16);
  lacc += __shfl_xor(lacc, 32);

  // dump per-wave partials; PV C/D layout: row(q) = quad*4+reg, col(d) = n16
#pragma unroll
  for (int r = 0; r < 4; ++r) {
    const int row = quad * 4 + r;
    lds_O[w][row][n16]      = O0[r];
    lds_O[w][row][16 + n16] = O1[r];
    lds_O[w][row][32 + n16] = O2[r];
    lds_O[w][row][48 + n16] = O3[r];
  }
  if (lane < 16) lds_l[w][lane] = lacc;
  __syncthreads();

  // merge 4 wave-partials, normalize, vectorized final store (no atomics)
  const int r = tid >> 4;
  const int c4 = (tid & 15) << 2;
  const float inv =
      1.0f / (lds_l[0][r] + lds_l[1][r] + lds_l[2][r] + lds_l[3][r]);
  f32x4 acc;
#pragma unroll
  for (int j = 0; j < 4; ++j)
    acc[j] = (lds_O[0][r][c4 + j] + lds_O[1][r][c4 + j] +
              lds_O[2][r][c4 + j] + lds_O[3][r][c4 + j]) * inv;
  *(f32x4*)(out + (size_t)(b * S_LEN + q0 + r) * DH + c4) = acc;
}

extern "C" void kernel_launch(void* const* d_in, const int* in_sizes, int n_in,
                              void* d_out, int out_size, void* d_ws, size_t ws_size,
                              hipStream_t stream) {
  const float* q = (const float*)d_in[0];
  const float* k = (const float*)d_in[1];
  const float* v = (const float*)d_in[2];
  const float* mask = (const float*)d_in[3];
  float* out = (float*)d_out;

  short* qb = (short*)d_ws;                                  // 2 MB
  short* kfrag = qb + (size_t)NBATCH * S_LEN * DH;           // 2 MB
  short* vfrag = kfrag + (size_t)NBATCH * S_LEN * DH;        // 2 MB

  cvt_q_kernel<<<(NBATCH * S_LEN * DH) / 1024, 256, 0, stream>>>(q, qb);
  cvt_frag_kernel<<<NBATCH * 128, 256, 0, stream>>>(k, v, kfrag, vfrag);
  fa_kernel<<<NBATCH * 256, 256, 0, stream>>>(qb, kfrag, vfrag, mask, out);
}